// Round 9
// baseline (318.899 us; speedup 1.0000x reference)
//
#include <hip/hip_runtime.h>

#define N_NODES 100000
#define N_EDGES 1250000
#define D 64
#define ED 32
#define CAP 40          // bucket capacity; Poisson(12.5) max-deg ~ 30
#define OVF_CAP 131072

typedef unsigned int uint;
typedef unsigned short ushort;

__device__ __forceinline__ uint bfr(float f) {
    uint u = __float_as_uint(f);
    return (u + 0x7FFFu + ((u >> 16) & 1u)) >> 16;
}
__device__ __forceinline__ uint pk(float a, float b) { return bfr(a) | (bfr(b) << 16); }
__device__ __forceinline__ float bfu(ushort s) { return __uint_as_float(((uint)s) << 16); }
__device__ __forceinline__ float bflo(uint v) { return __uint_as_float(v << 16); }
__device__ __forceinline__ float bfhi(uint v) { return __uint_as_float(v & 0xffff0000u); }

// ---------------- fused: bucket scatter (blocks 0..2047) | ea->bf16 conv (2048..3071) ----

__global__ void __launch_bounds__(256) scatconv_k(const int* __restrict__ row,
                                                  const int* __restrict__ col,
                                                  int* __restrict__ cursor,   // zeroed; becomes deg
                                                  int2* __restrict__ erec,
                                                  int4* __restrict__ ovf,
                                                  int* __restrict__ ovfcnt,
                                                  const float* __restrict__ ea,
                                                  ushort* __restrict__ eab) {
    const int bid = blockIdx.x;
    if (bid < 2048) {
        int i = bid * blockDim.x + threadIdx.x;
        const int stride = 2048 * blockDim.x;
        for (int e = i; e < N_EDGES; e += stride) {
            const int c = col[e];
            const int r = row[e];
            const int pos = atomicAdd(&cursor[c], 1);
            if (pos < CAP) {
                erec[(size_t)c * CAP + pos] = make_int2(r, e);
            } else {
                const int o = atomicAdd(ovfcnt, 1);
                if (o < OVF_CAP) ovf[o] = make_int4(c, r, e, 0);
            }
        }
    } else {
        // stream-convert ea (f32) -> eab (bf16), edge order
        int i = (bid - 2048) * blockDim.x + threadIdx.x;
        const int stride = 1024 * blockDim.x;
        const float4* s4 = (const float4*)ea;
        uint2* d2 = (uint2*)eab;
        const int NQ = N_EDGES * ED / 4;   // 10,000,000
        for (int k = i; k < NQ; k += stride) {
            const float4 v = s4[k];
            d2[k] = make_uint2(pk(v.x, v.y), pk(v.z, v.w));
        }
    }
}

// ---------------- xl16 = bf16(x @ lw^T) (blocks 0..1023) | Cmat,lwb (block 1024) ----------------

__global__ void __launch_bounds__(256) xl16_combine_k(const float* __restrict__ x,
                                                      const float* __restrict__ lw,
                                                      ushort* __restrict__ xl,
                                                      const float* __restrict__ ew,
                                                      const float* __restrict__ eb,
                                                      float* __restrict__ Cmat,
                                                      float* __restrict__ lwb) {
    const int bid = blockIdx.x;
    if (bid < 1024) {
        const int lane = threadIdx.x & 63;
        const int wid  = bid * 4 + (threadIdx.x >> 6);
        const int nw   = 1024 * 4;

        float w[D];
        const float4* lw4 = (const float4*)(lw + (size_t)lane * D);
#pragma unroll
        for (int q = 0; q < D / 4; ++q) {
            const float4 v = lw4[q];
            w[4*q+0] = v.x; w[4*q+1] = v.y; w[4*q+2] = v.z; w[4*q+3] = v.w;
        }
        for (int n = wid; n < N_NODES; n += nw) {
            const float4* xx = (const float4*)(x + (size_t)n * D);
            float d0 = 0.f, d1 = 0.f;
#pragma unroll
            for (int q = 0; q < D / 8; ++q) {
                const float4 v0 = xx[q];
                const float4 v1 = xx[q + 8];
                d0 = fmaf(v0.x, w[4*q+0], d0);  d0 = fmaf(v0.y, w[4*q+1], d0);
                d0 = fmaf(v0.z, w[4*q+2], d0);  d0 = fmaf(v0.w, w[4*q+3], d0);
                d1 = fmaf(v1.x, w[4*q+32], d1); d1 = fmaf(v1.y, w[4*q+33], d1);
                d1 = fmaf(v1.z, w[4*q+34], d1); d1 = fmaf(v1.w, w[4*q+35], d1);
            }
            xl[(size_t)n * D + lane] = (ushort)bfr(d0 + d1);
        }
    } else {
        for (int idx = threadIdx.x; idx < D * ED; idx += 256) {
            const int d = idx >> 5, j = idx & 31;
            float s = 0.f;
#pragma unroll
            for (int k = 0; k < D; ++k) s = fmaf(lw[d * D + k], ew[k * ED + j], s);
            Cmat[idx] = s;
        }
        if (threadIdx.x < D) {
            float s = 0.f;
#pragma unroll
            for (int k = 0; k < D; ++k) s = fmaf(lw[threadIdx.x * D + k], eb[k], s);
            lwb[threadIdx.x] = s;
        }
    }
}

// ---------------- aggregation + epilogue v2 (bf16 ea, quarter-wave reads) ----------------
// out[n][d] = inv*( segsum(xl[row]) + Cmat·segsum(ea) )[d] + [deg>0]*lwb[d] + lb[d]

__global__ void __launch_bounds__(256) agg_v2_k(const ushort* __restrict__ xl,
                                                const ushort* __restrict__ eab,
                                                const int* __restrict__ deg_,
                                                const int2* __restrict__ erec,
                                                const int4* __restrict__ ovf,
                                                const int* __restrict__ ovfcnt,
                                                const float* __restrict__ Cmat,
                                                const float* __restrict__ lwb,
                                                const float* __restrict__ lb,
                                                float* __restrict__ out) {
    const int lane = threadIdx.x & 63;
    const int sub  = lane & 15;       // dim pair index (dims 2*sub, 2*sub+1)
    const int g    = lane >> 4;       // edge group 0..3
    const int wid  = blockIdx.x * (blockDim.x >> 6) + (threadIdx.x >> 6);
    const int nw   = gridDim.x * (blockDim.x >> 6);

    const float lwbl = lwb[lane];
    const float lbl  = lb[lane];
    float w[ED];                      // Cmat row for this lane's output dim
    const float4* cm4 = (const float4*)(Cmat + (size_t)lane * ED);
#pragma unroll
    for (int q = 0; q < ED / 4; ++q) {
        const float4 v = cm4[q];
        w[4*q+0] = v.x; w[4*q+1] = v.y; w[4*q+2] = v.z; w[4*q+3] = v.w;
    }
    const int novf = *ovfcnt;

    for (int n = wid; n < N_NODES; n += nw) {
        const int deg  = deg_[n];
        const int degb = min(deg, CAP);
        float ax[8] = {0,0,0,0,0,0,0,0};
        float ael[4] = {0,0,0,0}, aeh[4] = {0,0,0,0};

        if (degb > 0) {
            const int2 rec = erec[(size_t)n * CAP + min(lane, degb - 1)];  // coalesced

            // ---- xl gathers: unpredicated full rounds + predicated tail ----
            const int full = degb & ~7;
            for (int k = 0; k < full; k += 8) {
                float vx[8];
#pragma unroll
                for (int i = 0; i < 8; ++i)
                    vx[i] = bfu(xl[(size_t)__shfl(rec.x, k + i) * D + lane]);
#pragma unroll
                for (int i = 0; i < 8; ++i) ax[i] += vx[i];
            }
            if (full < degb) {
                float vx[8];
#pragma unroll
                for (int i = 0; i < 8; ++i)
                    vx[i] = bfu(xl[(size_t)__shfl(rec.x, min(full + i, degb - 1)) * D + lane]);
#pragma unroll
                for (int i = 0; i < 8; ++i) ax[i] += (full + i < degb) ? vx[i] : 0.f;
            }

            // ---- eab reads: quarter-wave per edge (4 edges/instr), rounds of 8 ----
            const int nq = (degb + 3) >> 2;
            for (int t = 0; t < nq; t += 8) {
                uint v[8];
                int pv[8];
#pragma unroll
                for (int i = 0; i < 8; ++i) {
                    const int s  = (t + i) * 4 + g;
                    const int e0 = __shfl(rec.y, min(s, degb - 1));
                    pv[i] = (t + i < nq) && (s < degb);
                    v[i] = *(const uint*)(eab + (size_t)e0 * ED + sub * 2);
                }
#pragma unroll
                for (int i = 0; i < 8; ++i) {
                    ael[i & 3] += pv[i] ? bflo(v[i]) : 0.f;
                    aeh[i & 3] += pv[i] ? bfhi(v[i]) : 0.f;
                }
            }
        }

        // ---- overflow edges (correctness path; empty in practice) ----
        if (novf > 0) {
            for (int o = 0; o < novf; ++o) {
                const int4 v = ovf[o];
                if (v.x == n) {
                    ax[0] += bfu(xl[(size_t)v.y * D + lane]);
                    if (lane < 16) {
                        const uint u = *(const uint*)(eab + (size_t)v.z * ED + sub * 2);
                        ael[0] += bflo(u); aeh[0] += bfhi(u);
                    }
                }
            }
        }

        float axs = ((ax[0]+ax[1])+(ax[2]+ax[3])) + ((ax[4]+ax[5])+(ax[6]+ax[7]));
        float sl = (ael[0]+ael[1]) + (ael[2]+ael[3]);
        float sh = (aeh[0]+aeh[1]) + (aeh[2]+aeh[3]);
        sl += __shfl_xor(sl, 16); sl += __shfl_xor(sl, 32);  // sum over 4 groups
        sh += __shfl_xor(sh, 16); sh += __shfl_xor(sh, 32);
        // lane with sub=s now holds segsum(ea)[n][2s] (sl) and [2s+1] (sh), replicated

        float zd = axs;
#pragma unroll
        for (int s = 0; s < 16; ++s) {
            zd = fmaf(__shfl(sl, s), w[2*s],   zd);
            zd = fmaf(__shfl(sh, s), w[2*s+1], zd);
        }
        const float inv = 1.f / fmaxf((float)deg, 1.f);
        out[(size_t)n * D + lane] = fmaf(inv, zd, (deg > 0 ? lwbl : 0.f) + lbl);
    }
}

// ---------------- tier B: R8 kernels (f32 ea, no eab) ----------------

__global__ void __launch_bounds__(256) scatter_bucket_k(const int* __restrict__ row,
                                                        const int* __restrict__ col,
                                                        int* __restrict__ cursor,
                                                        int2* __restrict__ erec,
                                                        int4* __restrict__ ovf,
                                                        int* __restrict__ ovfcnt) {
    int i = blockIdx.x * blockDim.x + threadIdx.x;
    const int stride = gridDim.x * blockDim.x;
    for (int e = i; e < N_EDGES; e += stride) {
        const int c = col[e];
        const int r = row[e];
        const int pos = atomicAdd(&cursor[c], 1);
        if (pos < CAP) {
            erec[(size_t)c * CAP + pos] = make_int2(r, e);
        } else {
            const int o = atomicAdd(ovfcnt, 1);
            if (o < OVF_CAP) ovf[o] = make_int4(c, r, e, 0);
        }
    }
}

__global__ void __launch_bounds__(256) agg_bucket_k(const ushort* __restrict__ xl,
                                                    const float* __restrict__ ea,
                                                    const int* __restrict__ deg_,
                                                    const int2* __restrict__ erec,
                                                    const int4* __restrict__ ovf,
                                                    const int* __restrict__ ovfcnt,
                                                    const float* __restrict__ Cmat,
                                                    const float* __restrict__ lwb,
                                                    const float* __restrict__ lb,
                                                    float* __restrict__ out) {
    const int lane = threadIdx.x & 63;
    const int wid  = blockIdx.x * (blockDim.x >> 6) + (threadIdx.x >> 6);
    const int nw   = gridDim.x * (blockDim.x >> 6);

    const float lwbl = lwb[lane];
    const float lbl  = lb[lane];
    const float4* cm4 = (const float4*)(Cmat + (size_t)lane * ED);
    const int novf = *ovfcnt;

    for (int n = wid; n < N_NODES; n += nw) {
        const int deg  = deg_[n];
        const int degb = min(deg, CAP);
        float ax[8] = {0,0,0,0,0,0,0,0};
        float ae[8] = {0,0,0,0,0,0,0,0};

        if (degb > 0) {
            const int2 rec = erec[(size_t)n * CAP + min(lane, degb - 1)];
            const int full = degb & ~7;
            for (int k = 0; k < full; k += 8) {
                float vx[8];
#pragma unroll
                for (int i = 0; i < 8; ++i)
                    vx[i] = bfu(xl[(size_t)__shfl(rec.x, k + i) * D + lane]);
#pragma unroll
                for (int i = 0; i < 8; ++i) ax[i] += vx[i];
            }
            if (full < degb) {
                float vx[8];
#pragma unroll
                for (int i = 0; i < 8; ++i)
                    vx[i] = bfu(xl[(size_t)__shfl(rec.x, min(full + i, degb - 1)) * D + lane]);
#pragma unroll
                for (int i = 0; i < 8; ++i) ax[i] += (full + i < degb) ? vx[i] : 0.f;
            }
            const int npair = (degb + 1) >> 1;
            const int half = lane >> 5;
            for (int t = 0; t < npair; t += 8) {
                float ve[8];
                int pv[8];
#pragma unroll
                for (int i = 0; i < 8; ++i) {
                    const int p  = min(t + i, npair - 1);
                    const int slp = min(2 * p + half, degb - 1);
                    const int e0 = __shfl(rec.y, slp);
                    pv[i] = (t + i < npair) && (2 * p + half < degb);
                    ve[i] = ea[(size_t)e0 * ED + (lane & 31)];
                }
#pragma unroll
                for (int i = 0; i < 8; ++i) ae[i] += pv[i] ? ve[i] : 0.f;
            }
        }
        if (novf > 0) {
            for (int o = 0; o < novf; ++o) {
                const int4 v = ovf[o];
                if (v.x == n) {
                    ax[0] += bfu(xl[(size_t)v.y * D + lane]);
                    if (lane < ED) ae[0] += ea[(size_t)v.z * ED + lane];
                }
            }
        }
        float axs = ((ax[0]+ax[1])+(ax[2]+ax[3])) + ((ax[4]+ax[5])+(ax[6]+ax[7]));
        float aes = ((ae[0]+ae[1])+(ae[2]+ae[3])) + ((ae[4]+ae[5])+(ae[6]+ae[7]));
        aes += __shfl_xor(aes, 32);
        float zd = axs;
#pragma unroll
        for (int q = 0; q < ED / 4; ++q) {
            const float4 wv = cm4[q];
            zd = fmaf(__shfl(aes, 4*q+0), wv.x, zd);
            zd = fmaf(__shfl(aes, 4*q+1), wv.y, zd);
            zd = fmaf(__shfl(aes, 4*q+2), wv.z, zd);
            zd = fmaf(__shfl(aes, 4*q+3), wv.w, zd);
        }
        const float inv = 1.f / fmaxf((float)deg, 1.f);
        out[(size_t)n * D + lane] = fmaf(inv, zd, (deg > 0 ? lwbl : 0.f) + lbl);
    }
}

// ---------------- tier C (tiny ws): atomic version ----------------

__global__ void __launch_bounds__(256) edge_scatter_fb(
    const float* __restrict__ x, const int* __restrict__ ei,
    const float* __restrict__ ea, const float* __restrict__ ew,
    const float* __restrict__ eb, float* __restrict__ agg, float* __restrict__ deg) {
    const int lane = threadIdx.x & 63;
    const int wid  = blockIdx.x * (blockDim.x >> 6) + (threadIdx.x >> 6);
    const int nw   = gridDim.x * (blockDim.x >> 6);
    float w[ED];
#pragma unroll
    for (int k = 0; k < ED; ++k) w[k] = ew[lane * ED + k];
    const float b = eb[lane];
    for (int e = wid; e < N_EDGES; e += nw) {
        const int r = ei[e];
        const int c = ei[N_EDGES + e];
        const float4* ea4 = (const float4*)(ea + (size_t)e * ED);
        float acc = b;
#pragma unroll
        for (int q = 0; q < ED / 4; ++q) {
            float4 v = ea4[q];
            acc = fmaf(v.x, w[4*q+0], acc); acc = fmaf(v.y, w[4*q+1], acc);
            acc = fmaf(v.z, w[4*q+2], acc); acc = fmaf(v.w, w[4*q+3], acc);
        }
        acc += x[(size_t)r * D + lane];
        atomicAdd(&agg[(size_t)c * D + lane], acc);
        if (lane == 0) atomicAdd(&deg[c], 1.0f);
    }
}

__global__ void __launch_bounds__(256) node_linear_fb(
    float* __restrict__ agg, const float* __restrict__ deg,
    const float* __restrict__ lw, const float* __restrict__ lb) {
    const int lane = threadIdx.x & 63;
    const int wid  = blockIdx.x * (blockDim.x >> 6) + (threadIdx.x >> 6);
    const int nw   = gridDim.x * (blockDim.x >> 6);
    float w[D];
#pragma unroll
    for (int k = 0; k < D; ++k) w[k] = lw[lane * D + k];
    const float b = lb[lane];
    for (int n = wid; n < N_NODES; n += nw) {
        const float inv = 1.0f / fmaxf(deg[n], 1.0f);
        const float4* a4 = (const float4*)(agg + (size_t)n * D);
        float dot = 0.0f;
#pragma unroll
        for (int q = 0; q < D / 4; ++q) {
            float4 v = a4[q];
            dot = fmaf(v.x, w[4*q+0], dot); dot = fmaf(v.y, w[4*q+1], dot);
            dot = fmaf(v.z, w[4*q+2], dot); dot = fmaf(v.w, w[4*q+3], dot);
        }
        agg[(size_t)n * D + lane] = fmaf(inv, dot, b);
    }
}

// ---------------- launch ----------------

extern "C" void kernel_launch(void* const* d_in, const int* in_sizes, int n_in,
                              void* d_out, int out_size, void* d_ws, size_t ws_size,
                              hipStream_t stream) {
    const float* x  = (const float*)d_in[0];
    const int*   ei = (const int*)d_in[1];     // [2][E]: rows then cols
    const float* ea = (const float*)d_in[2];
    const float* lw = (const float*)d_in[3];
    const float* lb = (const float*)d_in[4];
    const float* ew = (const float*)d_in[5];
    const float* eb = (const float*)d_in[6];
    const int* row = ei;
    const int* col = ei + N_EDGES;

    char* ws = (char*)d_ws;
    float* zout = (float*)d_out;

    // ---- tier A layout (~127.3 MB) ----
    const size_t A_EREC = 0;                                    // 32,000,000
    const size_t A_EAB  = (size_t)N_NODES * CAP * 8;            // 80,000,000
    const size_t A_XL   = A_EAB + (size_t)N_EDGES * ED * 2;     // 12,800,000
    const size_t A_CNT  = A_XL + (size_t)N_NODES * D * 2;       //    400,000
    const size_t A_OVFC = A_CNT + (size_t)N_NODES * 4;          //         16
    const size_t A_OVF  = A_OVFC + 16;                          //  2,097,152
    const size_t A_CMAT = A_OVF + (size_t)OVF_CAP * 16;         //      8,192
    const size_t A_LWB  = A_CMAT + D * ED * 4;                  //        256
    const size_t REQ_A  = A_LWB + D * 4;

    // ---- tier B layout (R8, ~65.2 MB) ----
    const size_t B_EREC = 0;
    const size_t B_OVF  = (size_t)N_NODES * CAP * 8;
    const size_t B_XL   = B_OVF + (size_t)OVF_CAP * 16;
    const size_t B_CNT  = B_XL + (size_t)N_NODES * D * 2;
    const size_t B_OVFC = B_CNT + (size_t)N_NODES * 4;
    const size_t B_CMAT = B_OVFC + 16;
    const size_t B_LWB  = B_CMAT + D * ED * 4;
    const size_t REQ_B  = B_LWB + D * 4;

    if (ws_size >= REQ_A) {
        int2*   erec = (int2*)(ws + A_EREC);
        ushort* eab  = (ushort*)(ws + A_EAB);
        ushort* xl   = (ushort*)(ws + A_XL);
        int*    cnt  = (int*)(ws + A_CNT);
        int*    ovfc = (int*)(ws + A_OVFC);
        int4*   ovf  = (int4*)(ws + A_OVF);
        float*  Cmat = (float*)(ws + A_CMAT);
        float*  lwbv = (float*)(ws + A_LWB);

        hipMemsetAsync(cnt, 0, (size_t)N_NODES * sizeof(int) + 16, stream);
        scatconv_k     <<<3072, 256, 0, stream>>>(row, col, cnt, erec, ovf, ovfc, ea, eab);
        xl16_combine_k <<<1025, 256, 0, stream>>>(x, lw, xl, ew, eb, Cmat, lwbv);
        agg_v2_k       <<<4096, 256, 0, stream>>>(xl, eab, cnt, erec, ovf, ovfc,
                                                  Cmat, lwbv, lb, zout);
    } else if (ws_size >= REQ_B) {
        int2*   erec = (int2*)(ws + B_EREC);
        int4*   ovf  = (int4*)(ws + B_OVF);
        ushort* xl   = (ushort*)(ws + B_XL);
        int*    cnt  = (int*)(ws + B_CNT);
        int*    ovfc = (int*)(ws + B_OVFC);
        float*  Cmat = (float*)(ws + B_CMAT);
        float*  lwbv = (float*)(ws + B_LWB);

        hipMemsetAsync(cnt, 0, (size_t)N_NODES * sizeof(int) + 16, stream);
        scatter_bucket_k<<<2048, 256, 0, stream>>>(row, col, cnt, erec, ovf, ovfc);
        xl16_combine_k  <<<1025, 256, 0, stream>>>(x, lw, xl, ew, eb, Cmat, lwbv);
        agg_bucket_k    <<<4096, 256, 0, stream>>>(xl, ea, cnt, erec, ovf, ovfc,
                                                   Cmat, lwbv, lb, zout);
    } else {
        float* deg = (float*)d_ws;
        hipMemsetAsync(zout, 0, (size_t)N_NODES * D * sizeof(float), stream);
        hipMemsetAsync(deg, 0, (size_t)N_NODES * sizeof(float), stream);
        edge_scatter_fb<<<2048, 256, 0, stream>>>(x, ei, ea, ew, eb, zout, deg);
        node_linear_fb <<<1024, 256, 0, stream>>>(zout, deg, lw, lb);
    }
}